// Round 11
// baseline (54.872 us; speedup 1.0000x reference)
//
#include <hip/hip_runtime.h>

// Window_Crop: sliding-window avgpool over 5 aspect ratios + argmax (grps 0-3).
//
// Ratios (exact Python float semantics: 1024 // 25.6 == 39.0):
//   g0 (32,32) off 0      OH81 OW81 N6561
//   g1 (25,39) off 6561   OH88 OW74 N6512
//   g2 (39,25) off 13073  OH74 OW88 N6512
//   g3 (38,26) off 19585  OH75 OW87 N6525
//   g4 (26,38) off 26110  OH87 OW75 N6525   (excluded from argmax)
//   total 32635
//
// R1-R10 evidence: every schedule variant lands at 3.7-4.7 TB/s effective
// while fill=7 TB/s -> suspect per-instruction store cost (all variants
// emitted scalar global_store_dword; group offsets are !=0 mod 4 so the
// compiler can never merge). This round: QUAD-PACK stores -- runtime peel to
// a 16B-aligned base, each thread computes 4 consecutive windows and writes
// one float4 (global_store_dwordx4). 4x fewer store instrs + 4x fewer divs.
// Base structure = R7 (512 blocks x 2 images, T14 prefetch, 51KB LDS).

#define B_TOTAL 1024
#define GRID    512
#define HW      112
#define NPIX    (HW * HW)
#define NV4     (NPIX / 4)           // 3136 float4 per image
#define PITCH   113
#define TOTAL_W 32635
#define BLOCK   512
#define LDV4    7                    // ceil(3136 / 512)
#define SEG     28                   // 112 / 4 segments per scan line

template<int KH, int KW, int OFF, bool TRACK>
__device__ __forceinline__ void windows_group(const float* __restrict__ S,
                                              float* __restrict__ gout,
                                              int tid, float& bestv, int& besti) {
    constexpr int OH = HW - KH + 1;
    constexpr int OW = HW - KW + 1;
    constexpr int N  = OH * OW;
    constexpr int D  = KH * PITCH;        // bottom-row offset (dwords)
    constexpr float inv = 1.0f / (float)(KH * KW);
    float* const base = gout + OFF;
    // peel count so (base + a) is 16B-aligned -> float4 stores afterwards
    const int a  = (4 - (int)(((size_t)base >> 2) & 3)) & 3;
    const int NP = (N - a) >> 2;

    for (int p = tid; p < NP; p += BLOCK) {
        const int w4 = a + 4 * p;
        const int i  = w4 / OW;           // const divisor -> magic mul (1/pack)
        const int j  = w4 - i * OW;
        float4 r;
        if (j + 3 < OW) {                 // fast path: 4 windows share a row
            const float* St = S + i * PITCH + j;
            const float* Sb = St + D;
            r.x = (Sb[KW + 0] - St[KW + 0] - Sb[0] + St[0]) * inv;
            r.y = (Sb[KW + 1] - St[KW + 1] - Sb[1] + St[1]) * inv;
            r.z = (Sb[KW + 2] - St[KW + 2] - Sb[2] + St[2]) * inv;
            r.w = (Sb[KW + 3] - St[KW + 3] - Sb[3] + St[3]) * inv;
        } else {                          // row-crossing pack (~5% of packs)
            float rr[4];
            #pragma unroll
            for (int k = 0; k < 4; ++k) {
                const int w  = w4 + k;
                const int ii = w / OW;
                const int jj = w - ii * OW;
                const int A  = ii * PITCH + jj;
                rr[k] = (S[A + D + KW] - S[A + KW] - S[A + D] + S[A]) * inv;
            }
            r.x = rr[0]; r.y = rr[1]; r.z = rr[2]; r.w = rr[3];
        }
        *(float4*)(base + w4) = r;        // global_store_dwordx4
        if (TRACK) {  // index-explicit tie-break (processing order != w order)
            if (r.x > bestv || (r.x == bestv && OFF + w4     < besti)) { bestv = r.x; besti = OFF + w4;     }
            if (r.y > bestv || (r.y == bestv && OFF + w4 + 1 < besti)) { bestv = r.y; besti = OFF + w4 + 1; }
            if (r.z > bestv || (r.z == bestv && OFF + w4 + 2 < besti)) { bestv = r.z; besti = OFF + w4 + 2; }
            if (r.w > bestv || (r.w == bestv && OFF + w4 + 3 < besti)) { bestv = r.w; besti = OFF + w4 + 3; }
        }
    }

    // peel [0,a) + tail [a+4*NP, N): <= 6 windows, one thread each
    const int t0 = a + 4 * NP;
    const int nx = a + (N - t0);
    if (tid < nx) {
        const int w  = (tid < a) ? tid : (t0 + tid - a);
        const int ii = w / OW;
        const int jj = w - ii * OW;
        const int A  = ii * PITCH + jj;
        const float v = (S[A + D + KW] - S[A + KW] - S[A + D] + S[A]) * inv;
        base[w] = v;
        if (TRACK && (v > bestv || (v == bestv && OFF + w < besti))) {
            bestv = v; besti = OFF + w;
        }
    }
}

__device__ __forceinline__ void scans(float* __restrict__ S, int tid, int bl) {
    // row-wise prefix sums: 112 rows x 4 segments of 28; partials in regs,
    // shfl fixup. Across threads addresses stride 113: conflict-free.
    if (tid < HW * 4) {
        const int r = tid >> 2, s = tid & 3;
        float* row = &S[(r + 1) * PITCH];
        const int c0 = 1 + s * SEG;
        float pref[SEG];
        float run = 0.0f;
        #pragma unroll
        for (int k = 0; k < SEG; ++k) { run += row[c0 + k]; pref[k] = run; }
        const float v0 = __shfl(run, bl, 64), v1 = __shfl(run, bl + 1, 64),
                    v2 = __shfl(run, bl + 2, 64);
        float off = 0.0f;
        if (s > 0) off += v0;
        if (s > 1) off += v1;
        if (s > 2) off += v2;
        #pragma unroll
        for (int k = 0; k < SEG; ++k) row[c0 + k] = pref[k] + off;
    }
    __syncthreads();
    // column-wise prefix sums, same scheme (consecutive addrs across threads)
    if (tid < HW * 4) {
        const int c = tid >> 2, s = tid & 3;
        float* col = &S[c + 1];
        const int r0 = 1 + s * SEG;
        float pref[SEG];
        float run = 0.0f;
        #pragma unroll
        for (int k = 0; k < SEG; ++k) { run += col[(r0 + k) * PITCH]; pref[k] = run; }
        const float v0 = __shfl(run, bl, 64), v1 = __shfl(run, bl + 1, 64),
                    v2 = __shfl(run, bl + 2, 64);
        float off = 0.0f;
        if (s > 0) off += v0;
        if (s > 1) off += v1;
        if (s > 2) off += v2;
        #pragma unroll
        for (int k = 0; k < SEG; ++k) col[(r0 + k) * PITCH] = pref[k] + off;
    }
    __syncthreads();
}

__device__ __forceinline__ void write_img(float* __restrict__ S, const float4* v,
                                          int tid) {
    #pragma unroll
    for (int k = 0; k < LDV4; ++k) {
        const int i = tid + k * BLOCK;
        if (i < NV4) {
            const int r = i / (HW / 4);
            const int c = (i - r * (HW / 4)) * 4;
            float* dst = &S[(r + 1) * PITCH + (c + 1)];
            dst[0] = v[k].x; dst[1] = v[k].y; dst[2] = v[k].z; dst[3] = v[k].w;
        }
    }
}

__device__ __forceinline__ void windows_phase(const float* __restrict__ S,
                                              float* __restrict__ out, int b,
                                              int tid, int lane,
                                              float* wv, int* wi) {
    float bestv = -3.402823466e+38f;
    int   besti = 0;
    float* gout = out + 2 * B_TOTAL + (size_t)b * TOTAL_W;

    windows_group<32, 32,     0, true >(S, gout, tid, bestv, besti);
    windows_group<25, 39,  6561, true >(S, gout, tid, bestv, besti);
    windows_group<39, 25, 13073, true >(S, gout, tid, bestv, besti);
    windows_group<38, 26, 19585, true >(S, gout, tid, bestv, besti);
    windows_group<26, 38, 26110, false>(S, gout, tid, bestv, besti);

    #pragma unroll
    for (int d = 32; d > 0; d >>= 1) {
        const float ov = __shfl_down(bestv, d, 64);
        const int   oi = __shfl_down(besti, d, 64);
        if (ov > bestv || (ov == bestv && oi < besti)) { bestv = ov; besti = oi; }
    }
    if (lane == 0) { wv[tid >> 6] = bestv; wi[tid >> 6] = besti; }
    __syncthreads();
    if (tid == 0) {
        float bv = wv[0]; int bi = wi[0];
        #pragma unroll
        for (int k = 1; k < BLOCK / 64; ++k) {
            if (wv[k] > bv || (wv[k] == bv && wi[k] < bi)) { bv = wv[k]; bi = wi[k]; }
        }
        out[b]           = (float)bi;    // idx (exact in fp32: < 2^24)
        out[B_TOTAL + b] = bv;           // prop_scores
    }
}

__global__ __launch_bounds__(BLOCK)
void window_crop_kernel(const float* __restrict__ x, float* __restrict__ out) {
    __shared__ float S[PITCH * PITCH];           // 51,076 B integral image
    __shared__ float wv[BLOCK / 64];
    __shared__ int   wi[BLOCK / 64];

    const int tid  = threadIdx.x;
    const int lane = tid & 63;
    const int bl   = lane & ~3;

    const int bA = blockIdx.x;
    const int bB = blockIdx.x + GRID;

    // zero border row/col once; images only touch [1..112]^2
    for (int i = tid; i < PITCH; i += BLOCK) {
        S[i] = 0.0f;
        S[i * PITCH] = 0.0f;
    }

    // ---- image A: load -> LDS -> scans ----
    float4 va[LDV4];
    const float4* imgA = (const float4*)(x + (size_t)bA * NPIX);
    #pragma unroll
    for (int k = 0; k < LDV4; ++k) {
        const int i = tid + k * BLOCK;
        if (i < NV4) va[k] = imgA[i];
    }
    write_img(S, va, tid);
    __syncthreads();
    scans(S, tid, bl);

    // ---- issue image B's loads (consumed after A's window phase) ----
    float4 vb[LDV4];
    const float4* imgB = (const float4*)(x + (size_t)bB * NPIX);
    #pragma unroll
    for (int k = 0; k < LDV4; ++k) {
        const int i = tid + k * BLOCK;
        if (i < NV4) vb[k] = imgB[i];
    }

    // ---- image A: windows + argmax (write-heavy; B loads in flight) ----
    windows_phase(S, out, bA, tid, lane, wv, wi);
    __syncthreads();                 // all window reads of S done

    // ---- image B: LDS -> scans -> windows ----
    write_img(S, vb, tid);
    __syncthreads();
    scans(S, tid, bl);
    windows_phase(S, out, bB, tid, lane, wv, wi);
}

extern "C" void kernel_launch(void* const* d_in, const int* in_sizes, int n_in,
                              void* d_out, int out_size, void* d_ws, size_t ws_size,
                              hipStream_t stream) {
    const float* x = (const float*)d_in[0];
    float* out     = (float*)d_out;
    window_crop_kernel<<<GRID, BLOCK, 0, stream>>>(x, out);
}